// Round 1
// baseline (174.996 us; speedup 1.0000x reference)
//
#include <hip/hip_runtime.h>
#include <hip/hip_bf16.h>
#include <cmath>

#define NN 8192
#define FIN 256
#define FOUT 128

typedef short short8 __attribute__((ext_vector_type(8)));
typedef float f32x16 __attribute__((ext_vector_type(16)));

static __device__ __forceinline__ unsigned short f2bf(float f) {
    unsigned u = __float_as_uint(f);
    u += 0x7fffu + ((u >> 16) & 1u);
    return (unsigned short)(u >> 16);
}

// ---------------------------------------------------------------------------
// Pass A: h = input @ W^T + Wb  (bf16 MFMA, out^T form: h^T = W * input^T)
// Writes hT (bf16, [FOUT][NN]), s[i] = h[i]·a1, t[j] = h[j]·a2 + a_b
// Per block: 64 rows. 4 waves: nt = w>>1 (32-row n-tile), mh = w&1 (m-half).
// ---------------------------------------------------------------------------
__global__ __launch_bounds__(256, 2)
void gat_pass_a(const float* __restrict__ input, const float* __restrict__ W,
                const float* __restrict__ Wb, const float* __restrict__ aw,
                const float* __restrict__ ab, unsigned short* __restrict__ hT,
                float* __restrict__ s_out, float* __restrict__ t_out) {
    const int tid = threadIdx.x;
    const int w = tid >> 6, l = tid & 63;
    const int l5 = l >> 5, l31 = l & 31;
    const int nt = w >> 1, mh = w & 1;
    const int i0 = blockIdx.x * 64;
    const int i = i0 + nt * 32 + l31;

    f32x16 acc0 = {}; f32x16 acc1 = {};
    #pragma unroll
    for (int ks = 0; ks < FIN / 16; ++ks) {   // K16 steps
        const int c0 = ks * 16 + l5 * 8;
        // B frag: input[i][c0..c0+7] -> bf16  (B[k][n=i])
        const float4 b0 = *(const float4*)(input + (size_t)i * FIN + c0);
        const float4 b1 = *(const float4*)(input + (size_t)i * FIN + c0 + 4);
        short8 bf;
        bf[0]=(short)f2bf(b0.x); bf[1]=(short)f2bf(b0.y); bf[2]=(short)f2bf(b0.z); bf[3]=(short)f2bf(b0.w);
        bf[4]=(short)f2bf(b1.x); bf[5]=(short)f2bf(b1.y); bf[6]=(short)f2bf(b1.z); bf[7]=(short)f2bf(b1.w);
        {
            const int kcol = l31 + 32 * (2 * mh + 0);
            const float4 a0 = *(const float4*)(W + (size_t)kcol * FIN + c0);
            const float4 a1 = *(const float4*)(W + (size_t)kcol * FIN + c0 + 4);
            short8 af;
            af[0]=(short)f2bf(a0.x); af[1]=(short)f2bf(a0.y); af[2]=(short)f2bf(a0.z); af[3]=(short)f2bf(a0.w);
            af[4]=(short)f2bf(a1.x); af[5]=(short)f2bf(a1.y); af[6]=(short)f2bf(a1.z); af[7]=(short)f2bf(a1.w);
            acc0 = __builtin_amdgcn_mfma_f32_32x32x16_bf16(af, bf, acc0, 0, 0, 0);
        }
        {
            const int kcol = l31 + 32 * (2 * mh + 1);
            const float4 a0 = *(const float4*)(W + (size_t)kcol * FIN + c0);
            const float4 a1 = *(const float4*)(W + (size_t)kcol * FIN + c0 + 4);
            short8 af;
            af[0]=(short)f2bf(a0.x); af[1]=(short)f2bf(a0.y); af[2]=(short)f2bf(a0.z); af[3]=(short)f2bf(a0.w);
            af[4]=(short)f2bf(a1.x); af[5]=(short)f2bf(a1.y); af[6]=(short)f2bf(a1.z); af[7]=(short)f2bf(a1.w);
            acc1 = __builtin_amdgcn_mfma_f32_32x32x16_bf16(af, bf, acc1, 0, 0, 0);
        }
    }
    // Epilogue: +bias, write hT bf16, reduce s/t per row.
    __shared__ float sred[4][32];
    __shared__ float tred[4][32];
    float sacc = 0.f, tacc = 0.f;
    #pragma unroll
    for (int m = 0; m < 2; ++m) {
        #pragma unroll
        for (int r = 0; r < 16; ++r) {
            const int kcol = 32 * (2 * mh + m) + 4 * l5 + (r & 3) + 8 * (r >> 2);
            const float hv = (m ? acc1[r] : acc0[r]) + Wb[kcol];
            hT[(size_t)kcol * NN + i] = f2bf(hv);
            sacc += hv * aw[kcol];
            tacc += hv * aw[FOUT + kcol];
        }
    }
    sacc += __shfl_xor(sacc, 32);
    tacc += __shfl_xor(tacc, 32);
    if (l < 32) { sred[w][l] = sacc; tred[w][l] = tacc; }
    __syncthreads();
    if (mh == 0 && l < 32) {
        s_out[i] = sred[w][l] + sred[w + 1][l];
        t_out[i] = tred[w][l] + tred[w + 1][l] + ab[0];
    }
}

// ---------------------------------------------------------------------------
// Pass B: partial num[i][kcol] = sum_j p(i,j)*h[j][kcol], partial den[i].
// p(i,j) = adj[i][j]>0 ? exp(leaky_relu(s_i + t_j)) : 0   (t has +a_b folded)
// out^T = hT * P^T via 32x32x16 bf16 MFMA. P built in-register per lane.
// grid: (NN/64 row-blocks, nchunk j-chunks). 4 waves: nt=w>>1, mh=w&1.
// ---------------------------------------------------------------------------
struct StepRegs {
    int4   aj[4];   // adj ints:   [kk*2+q] -> j = jo + kk*16 + q*4 ..+3
    short8 ha[4];   // hT frags:   [m*2+kk]
    float4 tv[4];   // t values:   [kk*2+q]
};

static __device__ __forceinline__ void load_step(
        const int* __restrict__ adj, const unsigned short* __restrict__ hT,
        const float* __restrict__ t_in, size_t adjrow, size_t row0, size_t row1,
        int jo, StepRegs& S) {
    S.aj[0] = *(const int4*)(adj + adjrow + jo);
    S.aj[1] = *(const int4*)(adj + adjrow + jo + 4);
    S.aj[2] = *(const int4*)(adj + adjrow + jo + 16);
    S.aj[3] = *(const int4*)(adj + adjrow + jo + 20);
    S.tv[0] = *(const float4*)(t_in + jo);
    S.tv[1] = *(const float4*)(t_in + jo + 4);
    S.tv[2] = *(const float4*)(t_in + jo + 16);
    S.tv[3] = *(const float4*)(t_in + jo + 20);
    S.ha[0] = *(const short8*)(hT + row0 + jo);
    S.ha[1] = *(const short8*)(hT + row0 + jo + 16);
    S.ha[2] = *(const short8*)(hT + row1 + jo);
    S.ha[3] = *(const short8*)(hT + row1 + jo + 16);
}

static __device__ __forceinline__ void compute_step(
        const StepRegs& S, float si, f32x16& acc0, f32x16& acc1, float& dacc) {
    #pragma unroll
    for (int kk = 0; kk < 2; ++kk) {
        short8 bf;
        #pragma unroll
        for (int q = 0; q < 2; ++q) {
            const int4   a4 = S.aj[kk * 2 + q];
            const float4 t4 = S.tv[kk * 2 + q];
            float x, p;
            x = si + t4.x; x = fmaxf(x, 0.2f * x); p = __expf(x);
            p = (a4.x > 0) ? p : 0.f; dacc += p; bf[q * 4 + 0] = (short)f2bf(p);
            x = si + t4.y; x = fmaxf(x, 0.2f * x); p = __expf(x);
            p = (a4.y > 0) ? p : 0.f; dacc += p; bf[q * 4 + 1] = (short)f2bf(p);
            x = si + t4.z; x = fmaxf(x, 0.2f * x); p = __expf(x);
            p = (a4.z > 0) ? p : 0.f; dacc += p; bf[q * 4 + 2] = (short)f2bf(p);
            x = si + t4.w; x = fmaxf(x, 0.2f * x); p = __expf(x);
            p = (a4.w > 0) ? p : 0.f; dacc += p; bf[q * 4 + 3] = (short)f2bf(p);
        }
        acc0 = __builtin_amdgcn_mfma_f32_32x32x16_bf16(S.ha[0 * 2 + kk], bf, acc0, 0, 0, 0);
        acc1 = __builtin_amdgcn_mfma_f32_32x32x16_bf16(S.ha[1 * 2 + kk], bf, acc1, 0, 0, 0);
    }
}

__global__ __launch_bounds__(256, 2)
void gat_pass_b(const int* __restrict__ adj, const unsigned short* __restrict__ hT,
                const float* __restrict__ s_in, const float* __restrict__ t_in,
                float* __restrict__ numw, float* __restrict__ dpart, int jc) {
    const int tid = threadIdx.x;
    const int w = tid >> 6, l = tid & 63;
    const int l5 = l >> 5, l31 = l & 31;
    const int nt = w >> 1, mh = w & 1;
    const int i0 = blockIdx.x * 64;
    const int chunk = blockIdx.y;
    const int jbase = chunk * jc;
    const int i = i0 + nt * 32 + l31;
    const float si = s_in[i];
    const int ksteps = jc >> 5;

    const size_t adjrow = (size_t)i * NN;
    const size_t row0 = (size_t)(l31 + 32 * (2 * mh + 0)) * NN;
    const size_t row1 = (size_t)(l31 + 32 * (2 * mh + 1)) * NN;
    const int jo0 = jbase + l5 * 8;

    f32x16 acc0 = {}; f32x16 acc1 = {};
    float dacc = 0.f;

    StepRegs A, B;
    load_step(adj, hT, t_in, adjrow, row0, row1, jo0, A);
    for (int k = 0; k < ksteps; k += 2) {
        load_step(adj, hT, t_in, adjrow, row0, row1, jo0 + (k + 1) * 32, B);
        compute_step(A, si, acc0, acc1, dacc);
        if (k + 2 < ksteps)
            load_step(adj, hT, t_in, adjrow, row0, row1, jo0 + (k + 2) * 32, A);
        compute_step(B, si, acc0, acc1, dacc);
    }

    // Epilogue: write f32 partial numerators + denominator
    float* nump = numw + (size_t)chunk * NN * FOUT + (size_t)i * FOUT;
    #pragma unroll
    for (int m = 0; m < 2; ++m) {
        #pragma unroll
        for (int r = 0; r < 16; ++r) {
            const int kcol = 32 * (2 * mh + m) + 4 * l5 + (r & 3) + 8 * (r >> 2);
            nump[kcol] = (m ? acc1[r] : acc0[r]);
        }
    }
    if (mh == 0) {
        dacc += __shfl_xor(dacc, 32);   // dacc covered half (l5 split); both kk's summed in-lane
        if (l < 32) dpart[(size_t)chunk * NN + i] = dacc;
    }
}

// ---------------------------------------------------------------------------
// Pass C: out = elu( (sum_c num_c) / (sum_c den_c) )
// ---------------------------------------------------------------------------
__global__ void gat_reduce(const float* __restrict__ numw, const float* __restrict__ dpart,
                           float* __restrict__ out, int nchunk) {
    const int idx4 = blockIdx.x * blockDim.x + threadIdx.x;  // over NN*FOUT/4
    const int i = idx4 >> 5;                                  // 32 float4 per row
    float4 s = {0.f, 0.f, 0.f, 0.f};
    float d = 0.f;
    for (int c = 0; c < nchunk; ++c) {
        const float4 v = *(const float4*)(numw + (size_t)c * NN * FOUT + (size_t)idx4 * 4);
        s.x += v.x; s.y += v.y; s.z += v.z; s.w += v.w;
        d += dpart[(size_t)c * NN + i];
    }
    const float inv = 1.0f / d;
    float4 o;
    float v;
    v = s.x * inv; o.x = (v > 0.f) ? v : expm1f(v);
    v = s.y * inv; o.y = (v > 0.f) ? v : expm1f(v);
    v = s.z * inv; o.z = (v > 0.f) ? v : expm1f(v);
    v = s.w * inv; o.w = (v > 0.f) ? v : expm1f(v);
    *(float4*)(out + (size_t)idx4 * 4) = o;
}

// ---------------------------------------------------------------------------
extern "C" void kernel_launch(void* const* d_in, const int* in_sizes, int n_in,
                              void* d_out, int out_size, void* d_ws, size_t ws_size,
                              hipStream_t stream) {
    const float* input = (const float*)d_in[0];
    const int*   adj   = (const int*)d_in[1];
    const float* Ww    = (const float*)d_in[2];
    const float* Wb    = (const float*)d_in[3];
    const float* aw    = (const float*)d_in[4];
    const float* ab    = (const float*)d_in[5];
    float* out = (float*)d_out;

    char* ws = (char*)d_ws;
    unsigned short* hT = (unsigned short*)ws;                         // FOUT*NN bf16 = 2 MB
    float* s_buf = (float*)(ws + (size_t)FOUT * NN * 2);
    float* t_buf = s_buf + NN;
    float* dpart = t_buf + NN;

    int nchunk = 4;
    while (nchunk > 1) {
        size_t need = (size_t)FOUT * NN * 2 + 2 * (size_t)NN * 4
                    + (size_t)nchunk * NN * 4
                    + (size_t)nchunk * NN * FOUT * 4;
        if (need <= ws_size) break;
        nchunk >>= 1;
    }
    float* numw = dpart + (size_t)nchunk * NN;
    const int jc = NN / nchunk;

    gat_pass_a<<<dim3(NN / 64), 256, 0, stream>>>(input, Ww, Wb, aw, ab, hT, s_buf, t_buf);
    gat_pass_b<<<dim3(NN / 64, nchunk), 256, 0, stream>>>(adj, hT, s_buf, t_buf, numw, dpart, jc);
    gat_reduce<<<dim3((NN * FOUT / 4) / 256), 256, 0, stream>>>(numw, dpart, out, nchunk);
}

// Round 2
// 158.564 us; speedup vs baseline: 1.1036x; 1.1036x over previous
//
#include <hip/hip_runtime.h>
#include <hip/hip_bf16.h>
#include <cmath>

#define NN 8192
#define FIN 256
#define FOUT 128
#define NWORDS (NN / 32)

typedef short short8 __attribute__((ext_vector_type(8)));
typedef float f32x16 __attribute__((ext_vector_type(16)));

static __device__ __forceinline__ unsigned short f2bf(float f) {
    unsigned u = __float_as_uint(f);
    u += 0x7fffu + ((u >> 16) & 1u);
    return (unsigned short)(u >> 16);
}

// ---------------------------------------------------------------------------
// Compress: adj (int32, 256MB) -> bitmask (8MB). Pure streaming read.
// Each thread handles one 32-int segment = 128B contiguous.
// ---------------------------------------------------------------------------
__global__ __launch_bounds__(256)
void gat_compress(const int* __restrict__ adj, unsigned* __restrict__ bm) {
    const int seg = blockIdx.x * 256 + threadIdx.x;
    const int4* p = (const int4*)(adj + (size_t)seg * 32);
    unsigned m = 0;
    #pragma unroll
    for (int q = 0; q < 8; ++q) {
        const int4 v = p[q];
        m |= (v.x > 0 ? 1u : 0u) << (q * 4 + 0);
        m |= (v.y > 0 ? 1u : 0u) << (q * 4 + 1);
        m |= (v.z > 0 ? 1u : 0u) << (q * 4 + 2);
        m |= (v.w > 0 ? 1u : 0u) << (q * 4 + 3);
    }
    bm[seg] = m;
}

// ---------------------------------------------------------------------------
// Pass A: h = input @ W^T + Wb  (bf16 MFMA, h^T form). Also s = h·a1, t = h·a2+ab.
// ---------------------------------------------------------------------------
__global__ __launch_bounds__(256, 2)
void gat_pass_a(const float* __restrict__ input, const float* __restrict__ W,
                const float* __restrict__ Wb, const float* __restrict__ aw,
                const float* __restrict__ ab, unsigned short* __restrict__ hT,
                float* __restrict__ s_out, float* __restrict__ t_out) {
    const int tid = threadIdx.x;
    const int w = tid >> 6, l = tid & 63;
    const int l5 = l >> 5, l31 = l & 31;
    const int nt = w >> 1, mh = w & 1;
    const int i0 = blockIdx.x * 64;
    const int i = i0 + nt * 32 + l31;

    f32x16 acc0 = {}; f32x16 acc1 = {};
    #pragma unroll
    for (int ks = 0; ks < FIN / 16; ++ks) {
        const int c0 = ks * 16 + l5 * 8;
        const float4 b0 = *(const float4*)(input + (size_t)i * FIN + c0);
        const float4 b1 = *(const float4*)(input + (size_t)i * FIN + c0 + 4);
        short8 bf;
        bf[0]=(short)f2bf(b0.x); bf[1]=(short)f2bf(b0.y); bf[2]=(short)f2bf(b0.z); bf[3]=(short)f2bf(b0.w);
        bf[4]=(short)f2bf(b1.x); bf[5]=(short)f2bf(b1.y); bf[6]=(short)f2bf(b1.z); bf[7]=(short)f2bf(b1.w);
        {
            const int kcol = l31 + 32 * (2 * mh + 0);
            const float4 a0 = *(const float4*)(W + (size_t)kcol * FIN + c0);
            const float4 a1 = *(const float4*)(W + (size_t)kcol * FIN + c0 + 4);
            short8 af;
            af[0]=(short)f2bf(a0.x); af[1]=(short)f2bf(a0.y); af[2]=(short)f2bf(a0.z); af[3]=(short)f2bf(a0.w);
            af[4]=(short)f2bf(a1.x); af[5]=(short)f2bf(a1.y); af[6]=(short)f2bf(a1.z); af[7]=(short)f2bf(a1.w);
            acc0 = __builtin_amdgcn_mfma_f32_32x32x16_bf16(af, bf, acc0, 0, 0, 0);
        }
        {
            const int kcol = l31 + 32 * (2 * mh + 1);
            const float4 a0 = *(const float4*)(W + (size_t)kcol * FIN + c0);
            const float4 a1 = *(const float4*)(W + (size_t)kcol * FIN + c0 + 4);
            short8 af;
            af[0]=(short)f2bf(a0.x); af[1]=(short)f2bf(a0.y); af[2]=(short)f2bf(a0.z); af[3]=(short)f2bf(a0.w);
            af[4]=(short)f2bf(a1.x); af[5]=(short)f2bf(a1.y); af[6]=(short)f2bf(a1.z); af[7]=(short)f2bf(a1.w);
            acc1 = __builtin_amdgcn_mfma_f32_32x32x16_bf16(af, bf, acc1, 0, 0, 0);
        }
    }
    __shared__ float sred[4][32];
    __shared__ float tred[4][32];
    float sacc = 0.f, tacc = 0.f;
    #pragma unroll
    for (int m = 0; m < 2; ++m) {
        #pragma unroll
        for (int r = 0; r < 16; ++r) {
            const int kcol = 32 * (2 * mh + m) + 4 * l5 + (r & 3) + 8 * (r >> 2);
            const float hv = (m ? acc1[r] : acc0[r]) + Wb[kcol];
            hT[(size_t)kcol * NN + i] = f2bf(hv);
            sacc += hv * aw[kcol];
            tacc += hv * aw[FOUT + kcol];
        }
    }
    sacc += __shfl_xor(sacc, 32);
    tacc += __shfl_xor(tacc, 32);
    if (l < 32) { sred[w][l] = sacc; tred[w][l] = tacc; }
    __syncthreads();
    if (mh == 0 && l < 32) {
        s_out[i] = sred[w][l] + sred[w + 1][l];
        t_out[i] = tred[w][l] + tred[w + 1][l] + ab[0];
    }
}

// ---------------------------------------------------------------------------
// Pass B: partial num[i][kcol] = sum_j p(i,j)*h[j][kcol], partial den[i].
// p from bitmask (L2-resident) + s/t rank-1 scores. 2 independent waves per
// block; each wave owns 32 rows x all 128 kcols (no redundancy, no barriers).
// ---------------------------------------------------------------------------
__global__ __launch_bounds__(128, 3)
void gat_pass_b(const unsigned* __restrict__ bm, const unsigned short* __restrict__ hT,
                const float* __restrict__ s_in, const float* __restrict__ t_in,
                float* __restrict__ numw, float* __restrict__ dpart, int jc) {
    const int tid = threadIdx.x;
    const int w = tid >> 6, l = tid & 63;
    const int l5 = l >> 5, l31 = l & 31;
    const int i = blockIdx.x * 64 + w * 32 + l31;
    const int chunk = blockIdx.y;
    const int jb = chunk * jc;
    const float si = s_in[i];
    const int ksteps = jc >> 5;
    const unsigned* bmrow = bm + (size_t)i * NWORDS + (jb >> 5);

    f32x16 acc0 = {}, acc1 = {}, acc2 = {}, acc3 = {};
    float dacc = 0.f;

    for (int s = 0; s < ksteps; s += 2) {
        const uint2 wpair = *(const uint2*)(bmrow + s);
        #pragma unroll
        for (int h = 0; h < 2; ++h) {
            const unsigned word = h ? wpair.y : wpair.x;
            const int col0 = jb + (s + h) * 32;
            #pragma unroll
            for (int kk = 0; kk < 2; ++kk) {
                const int co = col0 + kk * 16 + l5 * 8;
                const float4 t0 = *(const float4*)(t_in + co);
                const float4 t1 = *(const float4*)(t_in + co + 4);
                const unsigned bsh = word >> (kk * 16 + l5 * 8);
                const float tv0 = t0.x, tv1 = t0.y, tv2 = t0.z, tv3 = t0.w;
                const float tv4 = t1.x, tv5 = t1.y, tv6 = t1.z, tv7 = t1.w;
                short8 bf;
                float x, p;
                x = si + tv0; x = fmaxf(x, 0.2f * x); p = __expf(x);
                p = (bsh & 1u)        ? p : 0.f; dacc += p; bf[0] = (short)f2bf(p);
                x = si + tv1; x = fmaxf(x, 0.2f * x); p = __expf(x);
                p = ((bsh >> 1) & 1u) ? p : 0.f; dacc += p; bf[1] = (short)f2bf(p);
                x = si + tv2; x = fmaxf(x, 0.2f * x); p = __expf(x);
                p = ((bsh >> 2) & 1u) ? p : 0.f; dacc += p; bf[2] = (short)f2bf(p);
                x = si + tv3; x = fmaxf(x, 0.2f * x); p = __expf(x);
                p = ((bsh >> 3) & 1u) ? p : 0.f; dacc += p; bf[3] = (short)f2bf(p);
                x = si + tv4; x = fmaxf(x, 0.2f * x); p = __expf(x);
                p = ((bsh >> 4) & 1u) ? p : 0.f; dacc += p; bf[4] = (short)f2bf(p);
                x = si + tv5; x = fmaxf(x, 0.2f * x); p = __expf(x);
                p = ((bsh >> 5) & 1u) ? p : 0.f; dacc += p; bf[5] = (short)f2bf(p);
                x = si + tv6; x = fmaxf(x, 0.2f * x); p = __expf(x);
                p = ((bsh >> 6) & 1u) ? p : 0.f; dacc += p; bf[6] = (short)f2bf(p);
                x = si + tv7; x = fmaxf(x, 0.2f * x); p = __expf(x);
                p = ((bsh >> 7) & 1u) ? p : 0.f; dacc += p; bf[7] = (short)f2bf(p);

                const size_t hoff = (size_t)l31 * NN + co;
                acc0 = __builtin_amdgcn_mfma_f32_32x32x16_bf16(*(const short8*)(hT + hoff),                    bf, acc0, 0, 0, 0);
                acc1 = __builtin_amdgcn_mfma_f32_32x32x16_bf16(*(const short8*)(hT + hoff + (size_t)32 * NN), bf, acc1, 0, 0, 0);
                acc2 = __builtin_amdgcn_mfma_f32_32x32x16_bf16(*(const short8*)(hT + hoff + (size_t)64 * NN), bf, acc2, 0, 0, 0);
                acc3 = __builtin_amdgcn_mfma_f32_32x32x16_bf16(*(const short8*)(hT + hoff + (size_t)96 * NN), bf, acc3, 0, 0, 0);
            }
        }
    }

    float* nump = numw + (size_t)chunk * NN * FOUT + (size_t)i * FOUT;
    #pragma unroll
    for (int r = 0; r < 16; ++r) {
        const int kc = 4 * l5 + (r & 3) + 8 * (r >> 2);
        nump[kc]      = acc0[r];
        nump[kc + 32] = acc1[r];
        nump[kc + 64] = acc2[r];
        nump[kc + 96] = acc3[r];
    }
    dacc += __shfl_xor(dacc, 32);
    if (l5 == 0) dpart[(size_t)chunk * NN + i] = dacc;
}

// ---------------------------------------------------------------------------
// Pass C: out = elu( (sum_c num_c) / (sum_c den_c) )
// ---------------------------------------------------------------------------
__global__ void gat_reduce(const float* __restrict__ numw, const float* __restrict__ dpart,
                           float* __restrict__ out, int nchunk) {
    const int idx4 = blockIdx.x * blockDim.x + threadIdx.x;
    const int i = idx4 >> 5;
    float4 s = {0.f, 0.f, 0.f, 0.f};
    float d = 0.f;
    for (int c = 0; c < nchunk; ++c) {
        const float4 v = *(const float4*)(numw + (size_t)c * NN * FOUT + (size_t)idx4 * 4);
        s.x += v.x; s.y += v.y; s.z += v.z; s.w += v.w;
        d += dpart[(size_t)c * NN + i];
    }
    const float inv = 1.0f / d;
    float4 o;
    float v;
    v = s.x * inv; o.x = (v > 0.f) ? v : expm1f(v);
    v = s.y * inv; o.y = (v > 0.f) ? v : expm1f(v);
    v = s.z * inv; o.z = (v > 0.f) ? v : expm1f(v);
    v = s.w * inv; o.w = (v > 0.f) ? v : expm1f(v);
    *(float4*)(out + (size_t)idx4 * 4) = o;
}

// ---------------------------------------------------------------------------
extern "C" void kernel_launch(void* const* d_in, const int* in_sizes, int n_in,
                              void* d_out, int out_size, void* d_ws, size_t ws_size,
                              hipStream_t stream) {
    const float* input = (const float*)d_in[0];
    const int*   adj   = (const int*)d_in[1];
    const float* Ww    = (const float*)d_in[2];
    const float* Wb    = (const float*)d_in[3];
    const float* aw    = (const float*)d_in[4];
    const float* ab    = (const float*)d_in[5];
    float* out = (float*)d_out;

    char* ws = (char*)d_ws;
    unsigned short* hT = (unsigned short*)ws;                 // 2 MB
    float* s_buf = (float*)(ws + (size_t)FOUT * NN * 2);      // 32 KB
    float* t_buf = s_buf + NN;                                // 32 KB
    unsigned* bm = (unsigned*)(t_buf + NN);                   // 8 MB

    int nchunk = 8;
    while (nchunk > 1) {
        size_t need = (size_t)FOUT * NN * 2 + 2 * (size_t)NN * 4
                    + (size_t)NN * NWORDS * 4
                    + (size_t)nchunk * NN * 4
                    + (size_t)nchunk * NN * FOUT * 4;
        if (need <= ws_size) break;
        nchunk >>= 1;
    }
    float* dpart = (float*)(bm + (size_t)NN * NWORDS);
    float* numw = dpart + (size_t)nchunk * NN;
    const int jc = NN / nchunk;

    gat_compress<<<dim3(NN * NWORDS / 256), 256, 0, stream>>>(adj, bm);
    gat_pass_a<<<dim3(NN / 64), 256, 0, stream>>>(input, Ww, Wb, aw, ab, hT, s_buf, t_buf);
    gat_pass_b<<<dim3(NN / 64, nchunk), 128, 0, stream>>>(bm, hT, s_buf, t_buf, numw, dpart, jc);
    gat_reduce<<<dim3((NN * FOUT / 4) / 256), 256, 0, stream>>>(numw, dpart, out, nchunk);
}